// Round 2
// baseline (81.523 us; speedup 1.0000x reference)
//
#include <hip/hip_runtime.h>
#include <stdint.h>

// Image constants from the reference module.
#define IMG_H 128
#define IMG_W 128

// One block = (one batch, 8 output pixels). 256 threads = 4 waves; each wave
// owns 2 pixels; the 64 lanes split the gaussian dimension.
// Phase 1: all 256 threads project the N gaussians into LDS (SoA float4,
//          conflict-free ds_read_b128 in phase 2).
// Phase 2: per-lane accumulation over N/64 gaussians, colors streamed from
//          global (48 KB fp32, L1/L2-resident; parallel path to the LDS port).
// Phase 3: 64-lane butterfly reduction, lane 0 finalizes + writes fp32.
__global__ __launch_bounds__(256, 1)
void gs_render(const float* __restrict__ pos,     // [N,3]
               const float* __restrict__ col,     // [N,3]
               const float* __restrict__ opa,     // [N,1]
               const float* __restrict__ scl,     // [N,1]
               const float* __restrict__ qvec,    // [B,4]
               const float* __restrict__ tvec,    // [B,3]
               const float* __restrict__ intr,    // [4]
               const int* __restrict__ chunkg,    // [1]
               float* __restrict__ out,           // [B,3,P]
               int N, int P, int tiles_per_batch)
{
    __shared__ float4 ldsA[4096];   // (-2k*u, -2k*v, c0, k) per gaussian — 64 KB

    const int tid  = threadIdx.x;
    const int b    = blockIdx.x / tiles_per_batch;
    const int tile = blockIdx.x % tiles_per_batch;

    // ---------------- Phase 1: project gaussians into LDS ----------------
    {
        float qw = qvec[b * 4 + 0];
        float qx = qvec[b * 4 + 1];
        float qy = qvec[b * 4 + 2];
        float qz = qvec[b * 4 + 3];
        float qn = rsqrtf(qw * qw + qx * qx + qy * qy + qz * qz);
        qw *= qn; qx *= qn; qy *= qn; qz *= qn;

        const float r00 = 1.0f - 2.0f * (qy * qy + qz * qz);
        const float r01 = 2.0f * (qx * qy - qz * qw);
        const float r02 = 2.0f * (qx * qz + qy * qw);
        const float r10 = 2.0f * (qx * qy + qz * qw);
        const float r11 = 1.0f - 2.0f * (qx * qx + qz * qz);
        const float r12 = 2.0f * (qy * qz - qx * qw);
        const float r20 = 2.0f * (qx * qz - qy * qw);
        const float r21 = 2.0f * (qy * qz + qx * qw);
        const float r22 = 1.0f - 2.0f * (qx * qx + qy * qy);

        const float tx = tvec[b * 3 + 0];
        const float ty = tvec[b * 3 + 1];
        const float tz = tvec[b * 3 + 2];

        const float fx = intr[0];
        const float fy = intr[1];
        const float cx = intr[2];
        const float cy = intr[3];

        for (int g = tid; g < N && g < 4096; g += 256) {
            float p0 = pos[3 * g + 0];
            float p1 = pos[3 * g + 1];
            float p2 = pos[3 * g + 2];

            float X = r00 * p0 + r01 * p1 + r02 * p2 + tx;
            float Y = r10 * p0 + r11 * p1 + r12 * p2 + ty;
            float Z = r20 * p0 + r21 * p1 + r22 * p2 + tz;

            float invZ = __fdividef(1.0f, Z);
            float u = X * invZ * fx + cx;
            float v = Y * invZ * fy + cy;

            float s   = scl[g];
            float var = s * s;
            float k   = -0.5f * __fdividef(1.0f, var);
            float op  = opa[g];
            float L   = __logf(fmaxf(op, 1e-30f));
            float c0  = fmaf(k, u * u + v * v, L);

            ldsA[g] = make_float4(-2.0f * k * u, -2.0f * k * v, c0, k);
        }
    }
    __syncthreads();

    // ---------------- Phase 2: per-pixel accumulation ----------------
    const int wave = tid >> 6;
    const int lane = tid & 63;

    const int p0 = tile * 8 + wave * 2;   // two pixels per wave
    const int p1 = p0 + 1;
    const float x0 = (float)(p0 & (IMG_W - 1));
    const float y0 = (float)(p0 >> 7);
    const float x1 = (float)(p1 & (IMG_W - 1));
    const float y1 = (float)(p1 >> 7);
    const float c20 = x0 * x0 + y0 * y0;
    const float c21 = x1 * x1 + y1 * y1;

    float d0 = 0.f, r0 = 0.f, g0 = 0.f, b0 = 0.f;
    float d1 = 0.f, r1 = 0.f, g1 = 0.f, b1 = 0.f;

    const int iters = N >> 6;   // N is a multiple of 64 (4096)
#pragma unroll 4
    for (int i = 0; i < iters; ++i) {
        const int g = (i << 6) | lane;
        float4 A = ldsA[g];

        const float* cp = col + 3 * g;
        float cr = cp[0];
        float cg = cp[1];
        float cb = cp[2];

        float t0 = fmaf(A.x, x0, fmaf(A.y, y0, fmaf(A.w, c20, A.z)));
        float t1 = fmaf(A.x, x1, fmaf(A.y, y1, fmaf(A.w, c21, A.z)));
        float w0 = __expf(t0);
        float w1 = __expf(t1);

        d0 += w0;              d1 += w1;
        r0 = fmaf(w0, cr, r0); r1 = fmaf(w1, cr, r1);
        g0 = fmaf(w0, cg, g0); g1 = fmaf(w1, cg, g1);
        b0 = fmaf(w0, cb, b0); b1 = fmaf(w1, cb, b1);
    }

    // ---------------- Phase 3: reduce + finalize ----------------
#pragma unroll
    for (int m = 32; m >= 1; m >>= 1) {
        d0 += __shfl_xor(d0, m, 64);
        r0 += __shfl_xor(r0, m, 64);
        g0 += __shfl_xor(g0, m, 64);
        b0 += __shfl_xor(b0, m, 64);
        d1 += __shfl_xor(d1, m, 64);
        r1 += __shfl_xor(r1, m, 64);
        g1 += __shfl_xor(g1, m, 64);
        b1 += __shfl_xor(b1, m, 64);
    }

    if (lane == 0) {
        int cg  = chunkg[0];
        int nch = (N + cg - 1) / cg;
        float eps = (float)nch * 1e-8f;

        float inv0 = 1.0f / fmaxf(d0 + eps, 1e-8f);
        float inv1 = 1.0f / fmaxf(d1 + eps, 1e-8f);

        float* ob = out + (size_t)b * 3 * P;
        ob[0 * P + p0] = r0 * inv0;
        ob[1 * P + p0] = g0 * inv0;
        ob[2 * P + p0] = b0 * inv0;
        ob[0 * P + p1] = r1 * inv1;
        ob[1 * P + p1] = g1 * inv1;
        ob[2 * P + p1] = b1 * inv1;
    }
}

extern "C" void kernel_launch(void* const* d_in, const int* in_sizes, int n_in,
                              void* d_out, int out_size, void* d_ws, size_t ws_size,
                              hipStream_t stream) {
    const float* pos  = (const float*)d_in[0];
    const float* col  = (const float*)d_in[1];
    const float* opa  = (const float*)d_in[2];
    const float* scl  = (const float*)d_in[3];
    const float* qv   = (const float*)d_in[4];
    const float* tv   = (const float*)d_in[5];
    const float* intr = (const float*)d_in[6];
    const int* chunkg = (const int*)d_in[8];
    float* out        = (float*)d_out;

    const int N = in_sizes[0] / 3;         // 4096 gaussians
    const int B = in_sizes[4] / 4;         // 2 batches
    const int P = out_size / (3 * B);      // 1024 output pixels per (b, channel)
    const int tiles = P / 8;               // 8 pixels per block

    gs_render<<<dim3(B * tiles), dim3(256), 0, stream>>>(
        pos, col, opa, scl, qv, tv, intr, chunkg, out, N, P, tiles);
}

// Round 3
// 77.951 us; speedup vs baseline: 1.0458x; 1.0458x over previous
//
#include <hip/hip_runtime.h>
#include <stdint.h>

// Image constants from the reference module.
#define IMG_W 128

// One block = (one batch, 8 output pixels). 1024 threads = 16 waves:
//   wave w -> pixel pair pp = w & 3 (pixels 2pp, 2pp+1),
//             gaussian slice s = w >> 2 (N/4 gaussians each).
// Phase 1: all 1024 threads project the N gaussians into LDS (SoA float4).
// Phase 2: per-lane accumulation over N/256 gaussians (16 iters), colors
//          streamed from global (48 KB fp32, L2-resident).
// Phase 3: 64-lane butterfly -> LDS partials -> 8 threads finalize + store.
__global__ __launch_bounds__(1024)
void gs_render(const float* __restrict__ pos,     // [N,3]
               const float* __restrict__ col,     // [N,3]
               const float* __restrict__ opa,     // [N,1]
               const float* __restrict__ scl,     // [N,1]
               const float* __restrict__ qvec,    // [B,4]
               const float* __restrict__ tvec,    // [B,3]
               const float* __restrict__ intr,    // [4]
               const int* __restrict__ chunkg,    // [1]
               float* __restrict__ out,           // [B,3,P]
               int N, int P, int tiles_per_batch)
{
    __shared__ float4 ldsA[4096];     // (-2k*u, -2k*v, c0, k) — 64 KB
    __shared__ float  part[16][8];    // per-wave partials {d0,r0,g0,b0,d1,r1,g1,b1}

    const int tid  = threadIdx.x;
    const int b    = blockIdx.x / tiles_per_batch;
    const int tile = blockIdx.x % tiles_per_batch;

    // ---------------- Phase 1: project gaussians into LDS ----------------
    {
        float qw = qvec[b * 4 + 0];
        float qx = qvec[b * 4 + 1];
        float qy = qvec[b * 4 + 2];
        float qz = qvec[b * 4 + 3];
        float qn = rsqrtf(qw * qw + qx * qx + qy * qy + qz * qz);
        qw *= qn; qx *= qn; qy *= qn; qz *= qn;

        const float r00 = 1.0f - 2.0f * (qy * qy + qz * qz);
        const float r01 = 2.0f * (qx * qy - qz * qw);
        const float r02 = 2.0f * (qx * qz + qy * qw);
        const float r10 = 2.0f * (qx * qy + qz * qw);
        const float r11 = 1.0f - 2.0f * (qx * qx + qz * qz);
        const float r12 = 2.0f * (qy * qz - qx * qw);
        const float r20 = 2.0f * (qx * qz - qy * qw);
        const float r21 = 2.0f * (qy * qz + qx * qw);
        const float r22 = 1.0f - 2.0f * (qx * qx + qy * qy);

        const float tx = tvec[b * 3 + 0];
        const float ty = tvec[b * 3 + 1];
        const float tz = tvec[b * 3 + 2];

        const float fx = intr[0];
        const float fy = intr[1];
        const float cx = intr[2];
        const float cy = intr[3];

        for (int g = tid; g < N && g < 4096; g += 1024) {
            float p0 = pos[3 * g + 0];
            float p1 = pos[3 * g + 1];
            float p2 = pos[3 * g + 2];

            float X = r00 * p0 + r01 * p1 + r02 * p2 + tx;
            float Y = r10 * p0 + r11 * p1 + r12 * p2 + ty;
            float Z = r20 * p0 + r21 * p1 + r22 * p2 + tz;

            float invZ = __fdividef(1.0f, Z);
            float u = X * invZ * fx + cx;
            float v = Y * invZ * fy + cy;

            float s   = scl[g];
            float var = s * s;
            float k   = -0.5f * __fdividef(1.0f, var);
            float op  = opa[g];
            float L   = __logf(fmaxf(op, 1e-30f));
            float c0  = fmaf(k, u * u + v * v, L);

            ldsA[g] = make_float4(-2.0f * k * u, -2.0f * k * v, c0, k);
        }
    }
    __syncthreads();

    // ---------------- Phase 2: sliced per-pixel accumulation ----------------
    const int wave  = tid >> 6;     // 0..15
    const int lane  = tid & 63;
    const int pp    = wave & 3;     // pixel pair within the 8-pixel tile
    const int slice = wave >> 2;    // gaussian slice 0..3

    const int p0 = tile * 8 + pp * 2;
    const int p1 = p0 + 1;
    const float x0 = (float)(p0 & (IMG_W - 1));
    const float y0 = (float)(p0 >> 7);
    const float x1 = (float)(p1 & (IMG_W - 1));
    const float y1 = (float)(p1 >> 7);
    const float c20 = x0 * x0 + y0 * y0;
    const float c21 = x1 * x1 + y1 * y1;

    float d0 = 0.f, r0 = 0.f, g0 = 0.f, b0 = 0.f;
    float d1 = 0.f, r1 = 0.f, g1 = 0.f, b1 = 0.f;

    const int slice_len = N >> 2;            // 1024
    const int iters     = slice_len >> 6;    // 16
    const int base      = slice * slice_len;

#pragma unroll 8
    for (int i = 0; i < iters; ++i) {
        const int g = base + (i << 6) + lane;
        float4 A = ldsA[g];

        const float* cp = col + 3 * g;
        float cr = cp[0];
        float cg = cp[1];
        float cb = cp[2];

        float t0 = fmaf(A.x, x0, fmaf(A.y, y0, fmaf(A.w, c20, A.z)));
        float t1 = fmaf(A.x, x1, fmaf(A.y, y1, fmaf(A.w, c21, A.z)));
        float w0 = __expf(t0);
        float w1 = __expf(t1);

        d0 += w0;              d1 += w1;
        r0 = fmaf(w0, cr, r0); r1 = fmaf(w1, cr, r1);
        g0 = fmaf(w0, cg, g0); g1 = fmaf(w1, cg, g1);
        b0 = fmaf(w0, cb, b0); b1 = fmaf(w1, cb, b1);
    }

    // ---------------- Phase 3: reduce + finalize ----------------
#pragma unroll
    for (int m = 32; m >= 1; m >>= 1) {
        d0 += __shfl_xor(d0, m, 64);
        r0 += __shfl_xor(r0, m, 64);
        g0 += __shfl_xor(g0, m, 64);
        b0 += __shfl_xor(b0, m, 64);
        d1 += __shfl_xor(d1, m, 64);
        r1 += __shfl_xor(r1, m, 64);
        g1 += __shfl_xor(g1, m, 64);
        b1 += __shfl_xor(b1, m, 64);
    }

    if (lane == 0) {
        part[wave][0] = d0; part[wave][1] = r0;
        part[wave][2] = g0; part[wave][3] = b0;
        part[wave][4] = d1; part[wave][5] = r1;
        part[wave][6] = g1; part[wave][7] = b1;
    }
    __syncthreads();

    if (tid < 8) {
        const int p    = tid;            // pixel within tile
        const int ppix = p >> 1;         // pixel pair
        const int off  = (p & 1) * 4;

        float d = 0.f, r = 0.f, g = 0.f, bl = 0.f;
#pragma unroll
        for (int s = 0; s < 4; ++s) {
            const int w = (s << 2) | ppix;
            d  += part[w][off + 0];
            r  += part[w][off + 1];
            g  += part[w][off + 2];
            bl += part[w][off + 3];
        }

        int cg  = chunkg[0];
        int nch = (N + cg - 1) / cg;
        float eps = (float)nch * 1e-8f;
        float inv = 1.0f / fmaxf(d + eps, 1e-8f);

        const int px = tile * 8 + p;
        float* ob = out + (size_t)b * 3 * P;
        ob[0 * P + px] = r  * inv;
        ob[1 * P + px] = g  * inv;
        ob[2 * P + px] = bl * inv;
    }
}

extern "C" void kernel_launch(void* const* d_in, const int* in_sizes, int n_in,
                              void* d_out, int out_size, void* d_ws, size_t ws_size,
                              hipStream_t stream) {
    const float* pos  = (const float*)d_in[0];
    const float* col  = (const float*)d_in[1];
    const float* opa  = (const float*)d_in[2];
    const float* scl  = (const float*)d_in[3];
    const float* qv   = (const float*)d_in[4];
    const float* tv   = (const float*)d_in[5];
    const float* intr = (const float*)d_in[6];
    const int* chunkg = (const int*)d_in[8];
    float* out        = (float*)d_out;

    const int N = in_sizes[0] / 3;         // 4096 gaussians
    const int B = in_sizes[4] / 4;         // 2 batches
    const int P = out_size / (3 * B);      // 1024 output pixels per (b, channel)
    const int tiles = P / 8;               // 8 pixels per block

    gs_render<<<dim3(B * tiles), dim3(1024), 0, stream>>>(
        pos, col, opa, scl, qv, tv, intr, chunkg, out, N, P, tiles);
}